// Round 9
// baseline (94.358 us; speedup 1.0000x reference)
//
#include <hip/hip_runtime.h>

#define NROW 8192
#define DIM  128
#define NSEG 16                     // 16 column chunks of 512 cols
#define BIGF 1e30f

typedef __attribute__((ext_vector_type(8))) short bf16x8;
typedef __attribute__((ext_vector_type(4))) float f32x4;

// ws layout (bytes):
//   [0, 2 MB)            xb2  : bf16, FRAGMENT-MAJOR: group g=row>>4 (512 groups),
//                               chunk c=0..15 (16B), slot row&15 -> every MFMA fragment
//                               load is a contiguous 1KB per wave instruction
//   2MB + [0, 32 KB)     sq   : f32 row sq-norms (fp32-exact)
//   2MB + [64, 576 KB)   posS : [NSEG][NROW] f32 partial hardest-pos d^2
//   2MB + [576,1088 KB)  negS : [NSEG][NROW] f32 partial hardest-neg d^2

__device__ __forceinline__ unsigned short f2bf(float f) {
    unsigned u = __float_as_uint(f);
    unsigned r = (u + 0x7fffu + ((u >> 16) & 1u)) >> 16;   // RNE
    return (unsigned short)r;
}

// one wave per row: bf16-convert into fragment-major layout + fp32 sq-norm
__global__ __launch_bounds__(256) void prep_kernel(const float* __restrict__ x,
                                                   unsigned short* __restrict__ xb2,
                                                   float* __restrict__ sq,
                                                   float* __restrict__ out) {
    int gtid = blockIdx.x * 256 + threadIdx.x;
    if (gtid == 0) out[0] = 0.0f;
    int row  = gtid >> 6;
    int lane = threadIdx.x & 63;
    const float* xr = x + (size_t)row * DIM;
    float a = xr[lane];
    float b = xr[lane + 64];
    // fragment-major dst: g*2048 + chunk*128 + slot*8 + within (ushort units)
    size_t d0 = (size_t)(row >> 4) * 2048 + (size_t)(lane >> 3) * 128
              + (size_t)(row & 15) * 8 + (lane & 7);
    xb2[d0]            = f2bf(a);   // elem lane      -> chunk lane>>3
    xb2[d0 + 8 * 128]  = f2bf(b);   // elem lane+64   -> chunk 8+(lane>>3)
    float s = a * a + b * b;
    #pragma unroll
    for (int o = 32; o > 0; o >>= 1) s += __shfl_down(s, o);
    if (lane == 0) sq[row] = s;
}

// Full Gram, 64 row-panels (128 rows) x 16 col-chunks (512 cols) = 1024 blocks.
// BARRIER-FREE global streaming: no LDS — B fragments loaded straight from the
// fragment-major layout (16KB tiles, L1/L2-resident; reuse is only 4 waves so
// LDS staging buys nothing but barrier-coupled vmcnt drains). jt loop is
// unrolled x2 so the scheduler software-pipelines jt+1's 16 B-loads under
// jt's MFMA+epilogue — the ≤1-tile load lookahead was the ~28us silent stall
// shared by all four previous structures. A frags register-resident; extrema
// in registers; per-seg plain stores (waves own disjoint rows -> no race).
__global__ __launch_bounds__(256, 3) void tile_mfma(const unsigned short* __restrict__ xb2,
                                                    const int* __restrict__ lbl,
                                                    const float* __restrict__ sq,
                                                    float* __restrict__ posS,
                                                    float* __restrict__ negS) {
    const int bid = blockIdx.x;
    const int rb  = bid >> 4;         // 0..63
    const int jq  = bid & 15;         // 0..15
    const int i0  = rb * 128;
    const int jbase = jq * 512;
    const int t    = threadIdx.x;
    const int lane = t & 63;
    const int w    = t >> 6;
    const int wr0  = i0 + w * 32;     // this wave's first row (4 waves x 32 rows)
    const int quad = lane >> 4;
    const int l15  = lane & 15;

    // ---- A fragments: 8 contiguous-1KB loads, once per block ----
    bf16x8 af[2][4];
    const int gA = wr0 >> 4;
    #pragma unroll
    for (int ti = 0; ti < 2; ti++)
        #pragma unroll
        for (int ks = 0; ks < 4; ks++)
            af[ti][ks] = *(const bf16x8*)(xb2 + (size_t)(gA + ti) * 2048 + (ks * 4 + quad) * 128 + l15 * 8);

    // per-lane row metadata
    int lbli[2][4];
    #pragma unroll
    for (int ti = 0; ti < 2; ti++) {
        int4 l4 = *(const int4*)(lbl + wr0 + ti * 16 + quad * 4);
        lbli[ti][0] = l4.x; lbli[ti][1] = l4.y; lbli[ti][2] = l4.z; lbli[ti][3] = l4.w;
    }
    const bool hasDiag = (i0 >= jbase) && (i0 < jbase + 512);

    float posm[2][4], negm[2][4];
    #pragma unroll
    for (int ti = 0; ti < 2; ti++)
        #pragma unroll
        for (int r = 0; r < 4; r++) { posm[ti][r] = -BIGF; negm[ti][r] = BIGF; }

    // jt unroll x2: the compiler interleaves the two bodies (deps only through
    // the associative min/max extrema), hoisting loads of jt+1 under jt compute.
    #pragma unroll 2
    for (int jt = 0; jt < 8; jt++) {
        const int j0 = jbase + jt * 64;
        const int gB = j0 >> 4;

        float sqj[4]; int lblj[4];
        #pragma unroll
        for (int tj = 0; tj < 4; tj++) {
            int c = j0 + tj * 16 + l15;
            sqj[tj]  = sq[c];
            lblj[tj] = lbl[c];
        }

        f32x4 acc[2][4];
        #pragma unroll
        for (int ti = 0; ti < 2; ti++)
            #pragma unroll
            for (int tj = 0; tj < 4; tj++) acc[ti][tj] = (f32x4){0.f, 0.f, 0.f, 0.f};

        #pragma unroll
        for (int ks = 0; ks < 4; ks++) {
            bf16x8 bfr[4];
            #pragma unroll
            for (int tj = 0; tj < 4; tj++)
                bfr[tj] = *(const bf16x8*)(xb2 + (size_t)(gB + tj) * 2048 + (ks * 4 + quad) * 128 + l15 * 8);
            #pragma unroll
            for (int ti = 0; ti < 2; ti++)
                #pragma unroll
                for (int tj = 0; tj < 4; tj++)
                    acc[ti][tj] = __builtin_amdgcn_mfma_f32_16x16x32_bf16(af[ti][ks], bfr[tj], acc[ti][tj], 0, 0, 0);
        }

        // epilogue: direct label compare (VALU busy-time ~11-12us total, not the stall)
        #pragma unroll
        for (int ti = 0; ti < 2; ti++) {
            const int rowg = wr0 + ti * 16 + quad * 4;
            #pragma unroll
            for (int tj = 0; tj < 4; tj++) {
                const int jc = j0 + tj * 16 + l15;
                #pragma unroll
                for (int r = 0; r < 4; r++) {
                    float sr = fmaf(-2.0f, acc[ti][tj][r], sqj[tj]);
                    bool same = (lbli[ti][r] == lblj[tj]);
                    bool self = hasDiag && (jc == rowg + r);
                    posm[ti][r] = fmaxf(posm[ti][r], (same && !self) ? sr : -BIGF);
                    negm[ti][r] = fminf(negm[ti][r], same ? BIGF : sr);
                }
            }
        }
    }

    // ---- flush: reduce across the 16 col-lanes, plain store per seg ----
    #pragma unroll
    for (int ti = 0; ti < 2; ti++)
        #pragma unroll
        for (int r = 0; r < 4; r++) {
            float p = posm[ti][r];
            float n = negm[ti][r];
            #pragma unroll
            for (int m = 8; m >= 1; m >>= 1) {
                p = fmaxf(p, __shfl_xor(p, m));
                n = fminf(n, __shfl_xor(n, m));
            }
            if (l15 == 0) {
                int row = wr0 + ti * 16 + quad * 4 + r;
                float sqi = sq[row];
                posS[jq * NROW + row] = fmaxf(0.0f, sqi + p);   // -BIG -> 0 (no positive here)
                negS[jq * NROW + row] = fmaxf(0.0f, sqi + n);   // clamp bf16-noise negatives
            }
        }
}

__global__ __launch_bounds__(256) void tri_final(const float* __restrict__ posS,
                                                 const float* __restrict__ negS,
                                                 const float* __restrict__ margin,
                                                 float* __restrict__ out) {
    int r = blockIdx.x * 256 + threadIdx.x;
    float p = 0.0f, n = BIGF;
    #pragma unroll
    for (int q = 0; q < NSEG; q++) {
        p = fmaxf(p, posS[q * NROW + r]);
        n = fminf(n, negS[q * NROW + r]);
    }
    float m = margin[0];
    float loss = fmaxf(sqrtf(p) - sqrtf(n) + m, 0.0f) * (1.0f / (float)NROW);
    #pragma unroll
    for (int o = 32; o > 0; o >>= 1) loss += __shfl_down(loss, o);
    __shared__ float wsum[4];
    int lane = threadIdx.x & 63, wv = threadIdx.x >> 6;
    if (lane == 0) wsum[wv] = loss;
    __syncthreads();
    if (threadIdx.x == 0) atomicAdd(out, wsum[0] + wsum[1] + wsum[2] + wsum[3]);
}

extern "C" void kernel_launch(void* const* d_in, const int* in_sizes, int n_in,
                              void* d_out, int out_size, void* d_ws, size_t ws_size,
                              hipStream_t stream) {
    const float* x      = (const float*)d_in[0];
    const int*   lbl    = (const int*)d_in[1];
    const float* margin = (const float*)d_in[2];
    float* out = (float*)d_out;

    char* ws = (char*)d_ws;
    unsigned short* xb2 = (unsigned short*)ws;
    float* sq   = (float*)(ws + (2u << 20));
    float* posS = (float*)(ws + (2u << 20) + (64u << 10));
    float* negS = (float*)(ws + (2u << 20) + (576u << 10));

    prep_kernel<<<2048, 256, 0, stream>>>(x, xb2, sq, out);
    tile_mfma<<<64 * NSEG, 256, 0, stream>>>(xb2, lbl, sq, posS, negS);
    tri_final<<<NROW / 256, 256, 0, stream>>>(posS, negS, margin, out);
}